// Round 2
// baseline (653.367 us; speedup 1.0000x reference)
//
#include <hip/hip_runtime.h>
#include <hip/hip_cooperative_groups.h>

namespace cg = cooperative_groups;

// DeepComplexRBF: 3 sequential layers of
//   dist_sq[i] = sum_j |y[j] - G[i,j]|^2 ; phi[i] = exp(-dist_sq/(2 s[i]))
//   y_new[o]   = sum_i W[o,i]*phi[i] + b[o]   (complex W, real phi)
// 576 MB of G/W streamed once -> HBM-bound, floor ~82-91 us.
// Single cooperative kernel, 6 phases, 5 grid syncs (removes 5 launch gaps).

#define D0 1024
#define H  4096

__device__ __forceinline__ float wave_sum(float v) {
#pragma unroll
    for (int off = 32; off > 0; off >>= 1) v += __shfl_down(v, off, 64);
    return v;
}

// blockDim is fixed at 256 -> stride 1024 floats per iteration.
__device__ __forceinline__ void stage_lds(float* dst, const float* __restrict__ src, int n) {
    for (int j = threadIdx.x * 4; j < n; j += 1024)
        *(float4*)(dst + j) = *(const float4*)(src + j);
    __syncthreads();
}

// wave-per-row: dist_sq + exp. G is (2, rows, cols); y staged in LDS.
__device__ __forceinline__ void phi_phase(
        const float* __restrict__ G, const float* __restrict__ s,
        const float* __restrict__ syr, const float* __restrict__ syi,
        float* __restrict__ phi, int rows, int cols,
        int gwave, int nwaves, int lane) {
    const float* Gre = G;
    const float* Gim = G + (size_t)rows * cols;
    for (int i = gwave; i < rows; i += nwaves) {
        const float* gre = Gre + (size_t)i * cols;
        const float* gim = Gim + (size_t)i * cols;
        float acc = 0.f;
#pragma unroll 4
        for (int j = lane * 4; j < cols; j += 256) {
            float4 gr = *(const float4*)(gre + j);
            float4 gi = *(const float4*)(gim + j);
            float4 yr = *(const float4*)(syr + j);
            float4 yi = *(const float4*)(syi + j);
            float dr, di;
            dr = yr.x - gr.x; di = yi.x - gi.x; acc += dr * dr + di * di;
            dr = yr.y - gr.y; di = yi.y - gi.y; acc += dr * dr + di * di;
            dr = yr.z - gr.z; di = yi.z - gi.z; acc += dr * dr + di * di;
            dr = yr.w - gr.w; di = yi.w - gi.w; acc += dr * dr + di * di;
        }
        acc = wave_sum(acc);
        if (lane == 0) phi[i] = expf(-acc / (2.0f * s[i]));
    }
}

// wave-per-row: y_new = W @ phi + b. W is (2, rows, cols); phi staged in LDS.
__device__ __forceinline__ void w_phase(
        const float* __restrict__ W, const float* __restrict__ b,
        const float* __restrict__ sphi,
        float* __restrict__ outre, float* __restrict__ outim,
        int rows, int cols, int gwave, int nwaves, int lane) {
    const float* Wre = W;
    const float* Wim = W + (size_t)rows * cols;
    const float* bre = b;
    const float* bim = b + rows;
    for (int o = gwave; o < rows; o += nwaves) {
        const float* wre = Wre + (size_t)o * cols;
        const float* wim = Wim + (size_t)o * cols;
        float ar = 0.f, ai = 0.f;
#pragma unroll 4
        for (int j = lane * 4; j < cols; j += 256) {
            float4 wr = *(const float4*)(wre + j);
            float4 wi = *(const float4*)(wim + j);
            float4 p  = *(const float4*)(sphi + j);
            ar += wr.x * p.x + wr.y * p.y + wr.z * p.z + wr.w * p.w;
            ai += wi.x * p.x + wi.y * p.y + wi.z * p.z + wi.w * p.w;
        }
        ar = wave_sum(ar);
        ai = wave_sum(ai);
        if (lane == 0) { outre[o] = ar + bre[o]; outim[o] = ai + bim[o]; }
    }
}

// block-per-row variant (for rows < total waves): all 4 waves split cols.
__device__ __forceinline__ void w_block(
        const float* __restrict__ W, const float* __restrict__ bre,
        const float* __restrict__ bim, const float* __restrict__ sphi,
        float* __restrict__ outre, float* __restrict__ outim,
        int rows, int cols, float* sred) {
    const float* Wre = W;
    const float* Wim = W + (size_t)rows * cols;
    const int tid = threadIdx.x, lane = tid & 63, wv = tid >> 6;
    for (int o = blockIdx.x; o < rows; o += gridDim.x) {
        const float* wre = Wre + (size_t)o * cols;
        const float* wim = Wim + (size_t)o * cols;
        float ar = 0.f, ai = 0.f;
#pragma unroll 4
        for (int j = tid * 4; j < cols; j += 1024) {
            float4 wr = *(const float4*)(wre + j);
            float4 wi = *(const float4*)(wim + j);
            float4 p  = *(const float4*)(sphi + j);
            ar += wr.x * p.x + wr.y * p.y + wr.z * p.z + wr.w * p.w;
            ai += wi.x * p.x + wi.y * p.y + wi.z * p.z + wi.w * p.w;
        }
        ar = wave_sum(ar);
        ai = wave_sum(ai);
        if (lane == 0) { sred[wv] = ar; sred[4 + wv] = ai; }
        __syncthreads();
        if (tid == 0) {
            outre[o] = sred[0] + sred[1] + sred[2] + sred[3] + bre[o];
            outim[o] = sred[4] + sred[5] + sred[6] + sred[7] + bim[o];
        }
        __syncthreads();
    }
}

__global__ __launch_bounds__(256, 4) void rbf_fused(
        const float* __restrict__ x,
        const float* __restrict__ W1, const float* __restrict__ b1,
        const float* __restrict__ G1, const float* __restrict__ s1,
        const float* __restrict__ W2, const float* __restrict__ b2,
        const float* __restrict__ G2, const float* __restrict__ s2,
        const float* __restrict__ W3, const float* __restrict__ b3,
        const float* __restrict__ G3, const float* __restrict__ s3,
        float* __restrict__ out, float* ws) {
    __shared__ float sm[2 * H + 8];   // 32.8 KB: union of {y planes} / {phi} + reduce scratch
    cg::grid_group grid = cg::this_grid();

    float* phi = ws;          // 4096
    float* yre = ws + H;      // 4096
    float* yim = ws + 2 * H;  // 4096 (contiguous with yre for one-shot staging)

    const int lane = threadIdx.x & 63;
    const int wave = threadIdx.x >> 6;
    const int gwave = blockIdx.x * 4 + wave;
    const int nwaves = gridDim.x * 4;

    // ---- Layer 1: y = x, shape (2, D0) contiguous
    stage_lds(sm, x, 2 * D0);
    phi_phase(G1, s1, sm, sm + D0, phi, H, D0, gwave, nwaves, lane);
    __threadfence();
    grid.sync();

    stage_lds(sm, phi, H);
    w_phase(W1, b1, sm, yre, yim, H, H, gwave, nwaves, lane);
    __threadfence();
    grid.sync();

    // ---- Layer 2
    stage_lds(sm, yre, 2 * H);
    phi_phase(G2, s2, sm, sm + H, phi, H, H, gwave, nwaves, lane);
    __threadfence();
    grid.sync();

    stage_lds(sm, phi, H);
    w_phase(W2, b2, sm, yre, yim, H, H, gwave, nwaves, lane);
    __threadfence();
    grid.sync();

    // ---- Layer 3
    stage_lds(sm, yre, 2 * H);
    phi_phase(G3, s3, sm, sm + H, phi, H, H, gwave, nwaves, lane);
    __threadfence();
    grid.sync();

    stage_lds(sm, phi, H);
    w_block(W3, b3, b3 + D0, sm, out, out + D0, D0, H, sm + 2 * H);
}

extern "C" void kernel_launch(void* const* d_in, const int* in_sizes, int n_in,
                              void* d_out, int out_size, void* d_ws, size_t ws_size,
                              hipStream_t stream) {
    const float* x  = (const float*)d_in[0];
    const float* W1 = (const float*)d_in[1];
    const float* b1 = (const float*)d_in[2];
    const float* G1 = (const float*)d_in[3];
    const float* s1 = (const float*)d_in[4];
    const float* W2 = (const float*)d_in[5];
    const float* b2 = (const float*)d_in[6];
    const float* G2 = (const float*)d_in[7];
    const float* s2 = (const float*)d_in[8];
    const float* W3 = (const float*)d_in[9];
    const float* b3 = (const float*)d_in[10];
    const float* G3 = (const float*)d_in[11];
    const float* s3 = (const float*)d_in[12];
    float* out = (float*)d_out;   // (2, 1024)
    float* ws  = (float*)d_ws;    // phi[H], yre[H], yim[H]

    // Co-residency: query occupancy (pure driver query, graph-capture safe),
    // cap at 1024 blocks (4/CU on 256 CUs; LDS 32.8 KB -> exactly 4/CU).
    int nb = 0;
    if (hipOccupancyMaxActiveBlocksPerMultiprocessor(&nb, (const void*)rbf_fused, 256, 0)
            != hipSuccess || nb < 1)
        nb = 1;
    long grid = (long)nb * 256;   // 256 CUs on MI355X
    if (grid > 1024) grid = 1024;

    void* args[] = {&x, &W1, &b1, &G1, &s1, &W2, &b2, &G2, &s2,
                    &W3, &b3, &G3, &s3, &out, &ws};
    hipLaunchCooperativeKernel((const void*)rbf_fused, dim3((int)grid), dim3(256),
                               args, 0, stream);
}

// Round 3
// 169.033 us; speedup vs baseline: 3.8653x; 3.8653x over previous
//
#include <hip/hip_runtime.h>

// DeepComplexRBF, single cooperative kernel.
//   dist_sq[i] = sum_j |y[j] - G[i,j]|^2 ; phi[i] = exp(-dist_sq/(2 s[i]))
//   y_new[o]   = sum_i W[o,i]*phi[i] + b[o]
// 576 MB of G/W streamed once -> HBM-bound, floor ~82 us @ 7 TB/s.
//
// Round-2 lesson: cg::grid.sync() + __threadfence() cost ~100 us/phase
// (device-scope L2 writeback/invalidate per block). Replacement: all
// cross-phase data (phi, y) goes through agent-scope RELAXED atomics
// (coherence-point ops, no cache maintenance needed), and the barrier is a
// relaxed flag protocol: slot store per block -> block-0 polls -> gen flag.
// __syncthreads() drains vmcnt, so data stores complete before slot stores.
//
// Occupancy: 512-thr blocks (8 waves), 32.8 KB LDS -> 4 blocks/CU = 32
// waves/CU (100%). Tasks = row-halves (SPLIT=2, or 8 for the 1024-row
// output layer): 8192 tasks ~ 8192 waves, pair-combine via LDS.

#define D0 1024
#define H  4096
#define NT 512
#define NWB 8   // waves per block

typedef unsigned long long u64;

__device__ __forceinline__ float wave_sum(float v) {
#pragma unroll
    for (int off = 32; off > 0; off >>= 1) v += __shfl_down(v, off, 64);
    return v;
}

// ---- coherence-point (cross-XCD safe) accessors ----
__device__ __forceinline__ void coh_store(float* p, float v) {
    __hip_atomic_store(p, v, __ATOMIC_RELAXED, __HIP_MEMORY_SCOPE_AGENT);
}
__device__ __forceinline__ int coh_ld_i(const int* p) {
    return __hip_atomic_load(const_cast<int*>(p), __ATOMIC_RELAXED, __HIP_MEMORY_SCOPE_AGENT);
}
__device__ __forceinline__ void coh_st_i(int* p, int v) {
    __hip_atomic_store(p, v, __ATOMIC_RELAXED, __HIP_MEMORY_SCOPE_AGENT);
}

// stage n floats (n even) from coherent global into LDS
__device__ __forceinline__ void stage_coh(float* dst, const float* src, int n) {
    u64* d = (u64*)dst;
    u64* s = const_cast<u64*>((const u64*)src);
    for (int j = threadIdx.x; j < n / 2; j += NT)
        d[j] = __hip_atomic_load(&s[j], __ATOMIC_RELAXED, __HIP_MEMORY_SCOPE_AGENT);
    __syncthreads();
}
// stage read-only input (plain, vectorized)
__device__ __forceinline__ void stage_plain(float* dst, const float* __restrict__ src, int n) {
    for (int j = threadIdx.x * 4; j < n; j += NT * 4)
        *(float4*)(dst + j) = *(const float4*)(src + j);
    __syncthreads();
}

// relaxed-flag grid barrier. slots[b] for b>=1; gen separate line.
__device__ __forceinline__ void gridbar(int* slots, int* gen, int phase) {
    __syncthreads();   // all waves done + vmcnt drained (stores at coherence point)
    const int nb = gridDim.x;
    if (blockIdx.x == 0) {
        for (int i = threadIdx.x + 1; i < nb; i += NT)
            while (coh_ld_i(&slots[i]) < phase) __builtin_amdgcn_s_sleep(1);
        __syncthreads();
        if (threadIdx.x == 0) coh_st_i(gen, phase);
    } else {
        if (threadIdx.x == 0) {
            coh_st_i(&slots[blockIdx.x], phase);
            while (coh_ld_i(gen) < phase) __builtin_amdgcn_s_sleep(4);
        }
        __syncthreads();
    }
}

// ---- phase workers. TASKS = ROWS*SPLIT half/eighth-rows; SPLIT consecutive
// waves (same block) cover one row; combine partials via LDS sred. ----
template <int COLS, int SPLIT, int ROWS>
__device__ __forceinline__ void do_phi(
        const float* __restrict__ G, const float* __restrict__ sv,
        float* phi, const float* syr, const float* syi, float* sred,
        int gwave, int nwaves, int lane, int w) {
    constexpr int LEN = COLS / SPLIT;
    constexpr int TASKS = ROWS * SPLIT;
    const int kmax = (TASKS + nwaves - 1) / nwaves;
    for (int k = 0; k < kmax; ++k) {
        const int t = gwave + k * nwaves;
        float part = 0.f;
        if (t < TASKS) {
            const int row = t / SPLIT, sub = t % SPLIT;
            const float* gre = G + (size_t)row * COLS + sub * LEN;
            const float* gim = gre + (size_t)ROWS * COLS;
            const float* yr = syr + sub * LEN;
            const float* yi = syi + sub * LEN;
            float acc = 0.f;
#pragma unroll 4
            for (int j = lane * 4; j < LEN; j += 256) {
                float4 gr = *(const float4*)(gre + j);
                float4 gi = *(const float4*)(gim + j);
                float4 y0 = *(const float4*)(yr + j);
                float4 y1 = *(const float4*)(yi + j);
                float dr, di;
                dr = y0.x - gr.x; di = y1.x - gi.x; acc += dr * dr + di * di;
                dr = y0.y - gr.y; di = y1.y - gi.y; acc += dr * dr + di * di;
                dr = y0.z - gr.z; di = y1.z - gi.z; acc += dr * dr + di * di;
                dr = y0.w - gr.w; di = y1.w - gi.w; acc += dr * dr + di * di;
            }
            part = wave_sum(acc);
        }
        if (lane == 0) sred[w] = part;
        __syncthreads();
        if (t < TASKS && (w % SPLIT) == 0 && lane == 0) {
            float d = 0.f;
#pragma unroll
            for (int q = 0; q < SPLIT; ++q) d += sred[w + q];
            const int row = t / SPLIT;
            coh_store(&phi[row], expf(-d / (2.0f * sv[row])));
        }
        __syncthreads();
    }
}

template <int COLS, int SPLIT, int ROWS, bool COH>
__device__ __forceinline__ void do_w(
        const float* __restrict__ W, const float* __restrict__ b,
        const float* sphi, float* ore, float* oim, float* sred,
        int gwave, int nwaves, int lane, int w) {
    constexpr int LEN = COLS / SPLIT;
    constexpr int TASKS = ROWS * SPLIT;
    const int kmax = (TASKS + nwaves - 1) / nwaves;
    for (int k = 0; k < kmax; ++k) {
        const int t = gwave + k * nwaves;
        float ar = 0.f, ai = 0.f;
        if (t < TASKS) {
            const int row = t / SPLIT, sub = t % SPLIT;
            const float* wre = W + (size_t)row * COLS + sub * LEN;
            const float* wim = wre + (size_t)ROWS * COLS;
            const float* p = sphi + sub * LEN;
            float a0 = 0.f, a1 = 0.f;
#pragma unroll 4
            for (int j = lane * 4; j < LEN; j += 256) {
                float4 wr = *(const float4*)(wre + j);
                float4 wi = *(const float4*)(wim + j);
                float4 pv = *(const float4*)(p + j);
                a0 += wr.x * pv.x + wr.y * pv.y + wr.z * pv.z + wr.w * pv.w;
                a1 += wi.x * pv.x + wi.y * pv.y + wi.z * pv.z + wi.w * pv.w;
            }
            ar = wave_sum(a0);
            ai = wave_sum(a1);
        }
        if (lane == 0) { sred[w] = ar; sred[NWB + w] = ai; }
        __syncthreads();
        if (t < TASKS && (w % SPLIT) == 0 && lane == 0) {
            float vr = 0.f, vi = 0.f;
#pragma unroll
            for (int q = 0; q < SPLIT; ++q) { vr += sred[w + q]; vi += sred[NWB + w + q]; }
            const int row = t / SPLIT;
            vr += b[row];
            vi += b[ROWS + row];
            if (COH) { coh_store(&ore[row], vr); coh_store(&oim[row], vi); }
            else     { ore[row] = vr; oim[row] = vi; }
        }
        __syncthreads();
    }
}

__global__ __launch_bounds__(NT, 8) void rbf_fused(
        const float* __restrict__ x,
        const float* __restrict__ W1, const float* __restrict__ b1,
        const float* __restrict__ G1, const float* __restrict__ s1,
        const float* __restrict__ W2, const float* __restrict__ b2,
        const float* __restrict__ G2, const float* __restrict__ s2,
        const float* __restrict__ W3, const float* __restrict__ b3,
        const float* __restrict__ G3, const float* __restrict__ s3,
        float* __restrict__ out, float* ws, int* bar) {
    __shared__ float sm[2 * H + 16];
    float* sred = sm + 2 * H;
    float* phi = ws;
    float* yre = ws + H;
    float* yim = ws + 2 * H;
    int* slots = bar;
    int* gen = bar + 1536;

    const int lane = threadIdx.x & 63;
    const int w = threadIdx.x >> 6;
    const int gwave = blockIdx.x * NWB + w;
    const int nwaves = gridDim.x * NWB;

    // ---- L1: phi1 = rbf(G1, x)
    stage_plain(sm, x, 2 * D0);
    do_phi<D0, 2, H>(G1, s1, phi, sm, sm + D0, sred, gwave, nwaves, lane, w);
    gridbar(slots, gen, 1);

    stage_coh(sm, phi, H);
    do_w<H, 2, H, true>(W1, b1, sm, yre, yim, sred, gwave, nwaves, lane, w);
    gridbar(slots, gen, 2);

    // ---- L2
    stage_coh(sm, yre, 2 * H);
    do_phi<H, 2, H>(G2, s2, phi, sm, sm + H, sred, gwave, nwaves, lane, w);
    gridbar(slots, gen, 3);

    stage_coh(sm, phi, H);
    do_w<H, 2, H, true>(W2, b2, sm, yre, yim, sred, gwave, nwaves, lane, w);
    gridbar(slots, gen, 4);

    // ---- L3
    stage_coh(sm, yre, 2 * H);
    do_phi<H, 2, H>(G3, s3, phi, sm, sm + H, sred, gwave, nwaves, lane, w);
    gridbar(slots, gen, 5);

    stage_coh(sm, phi, H);
    do_w<H, 8, D0, false>(W3, b3, sm, out, out + D0, sred, gwave, nwaves, lane, w);
}

extern "C" void kernel_launch(void* const* d_in, const int* in_sizes, int n_in,
                              void* d_out, int out_size, void* d_ws, size_t ws_size,
                              hipStream_t stream) {
    const float* x  = (const float*)d_in[0];
    const float* W1 = (const float*)d_in[1];
    const float* b1 = (const float*)d_in[2];
    const float* G1 = (const float*)d_in[3];
    const float* s1 = (const float*)d_in[4];
    const float* W2 = (const float*)d_in[5];
    const float* b2 = (const float*)d_in[6];
    const float* G2 = (const float*)d_in[7];
    const float* s2 = (const float*)d_in[8];
    const float* W3 = (const float*)d_in[9];
    const float* b3 = (const float*)d_in[10];
    const float* G3 = (const float*)d_in[11];
    const float* s3 = (const float*)d_in[12];
    float* out = (float*)d_out;   // (2, 1024)
    float* ws  = (float*)d_ws;    // phi[H], yre[H], yim[H], then barrier ints
    int* bar = (int*)(ws + 3 * H);

    // zero barrier state each call (ws is poisoned 0xAA once, never restored)
    hipMemsetAsync(bar, 0, 2048 * sizeof(int), stream);

    int nb = 0;
    if (hipOccupancyMaxActiveBlocksPerMultiprocessor(&nb, (const void*)rbf_fused, NT, 0)
            != hipSuccess || nb < 1)
        nb = 4;
    long grid = (long)nb * 256;   // 256 CUs
    if (grid > 1024) grid = 1024;

    void* args[] = {&x, &W1, &b1, &G1, &s1, &W2, &b2, &G2, &s2,
                    &W3, &b3, &G3, &s3, &out, &ws, &bar};
    hipLaunchCooperativeKernel((const void*)rbf_fused, dim3((int)grid), dim3(NT),
                               args, 0, stream);
}